// Round 6
// baseline (229.964 us; speedup 1.0000x reference)
//
#include <hip/hip_runtime.h>
#include <stdint.h>

typedef unsigned int uint;
typedef unsigned short ushort_t;
typedef float f32x4 __attribute__((ext_vector_type(4)));

#define NPTS 500000
#define NC 256
#define SPAIRS 600000      // == 64 * 9375 exactly (full waves)
#define FS 14
#define F3 2744            // 14^3
#define VOXT (NC * F3)     // 702464

// ---------- helpers ----------
__device__ __forceinline__ uint encF(float f) {
    uint u = __float_as_uint(f);
    return (u & 0x80000000u) ? ~u : (u | 0x80000000u);
}
__device__ __forceinline__ float decF(uint e) {
    uint u = (e & 0x80000000u) ? (e ^ 0x80000000u) : ~e;
    return __uint_as_float(u);
}
// ids may arrive as int32 (jax x64 off) or int64. Sorted cids: mid values ~128,
// so for int64 the odd int32 words (high) are 0; for int32 they're nonzero.
__device__ __forceinline__ uint detect64(const void* cids) {
    const int* p = (const int*)cids;
    int z = 0;
    #pragma unroll
    for (int k = 0; k < 5; ++k) z += (p[300001 + 2 * k] == 0) ? 1 : 0;
    return (z >= 3) ? 1u : 0u;
}
__device__ __forceinline__ int loadId(const void* p, int i, uint is64) {
    return is64 ? (int)((const long long*)p)[i] : ((const int*)p)[i];
}

// ---------- kernel 1: per-cluster count/sum(f64)/min/max — wave-segmented reduce ----------
__global__ __launch_bounds__(256) void k_stats(const void* cids, const void* pids,
        const float* coords,
        double* gsum, uint* gcnt, uint* gmin, uint* gmax) {
    __shared__ double sSum[NC][3];
    __shared__ uint   sCnt[NC];
    __shared__ uint   sMin[NC][3];
    __shared__ uint   sMax[NC][3];
    int tid = threadIdx.x;
    for (int c = tid; c < NC; c += 256) {
        sCnt[c] = 0u;
        for (int d = 0; d < 3; ++d) { sSum[c][d] = 0.0; sMin[c][d] = 0xFFFFFFFFu; sMax[c][d] = 0u; }
    }
    __syncthreads();
    uint is64 = detect64(cids);
    int s = blockIdx.x * 256 + tid;
    bool valid = s < SPAIRS;
    int sc = valid ? s : SPAIRS - 1;
    int cid = loadId(cids, sc, is64);
    int pid = loadId(pids, sc, is64);
    float x = coords[3 * pid + 0];
    float y = coords[3 * pid + 1];
    float z = coords[3 * pid + 2];
    int lane = tid & 63;
    int cid0 = __shfl(cid, 0, 64), cid63 = __shfl(cid, 63, 64);
    if (cid0 == cid63) {
        uint nval = (uint)__popcll(__ballot(valid));
        double dx = valid ? (double)x : 0.0;
        double dy = valid ? (double)y : 0.0;
        double dz = valid ? (double)z : 0.0;
        float mnx = valid ? x : INFINITY,  mny = valid ? y : INFINITY,  mnz = valid ? z : INFINITY;
        float mxx = valid ? x : -INFINITY, mxy = valid ? y : -INFINITY, mxz = valid ? z : -INFINITY;
        #pragma unroll
        for (int st = 1; st < 64; st <<= 1) {
            dx += __shfl_xor(dx, st, 64);
            dy += __shfl_xor(dy, st, 64);
            dz += __shfl_xor(dz, st, 64);
            mnx = fminf(mnx, __shfl_xor(mnx, st, 64));
            mny = fminf(mny, __shfl_xor(mny, st, 64));
            mnz = fminf(mnz, __shfl_xor(mnz, st, 64));
            mxx = fmaxf(mxx, __shfl_xor(mxx, st, 64));
            mxy = fmaxf(mxy, __shfl_xor(mxy, st, 64));
            mxz = fmaxf(mxz, __shfl_xor(mxz, st, 64));
        }
        if (lane == 0 && nval) {
            atomicAdd(&sCnt[cid0], nval);
            unsafeAtomicAdd(&sSum[cid0][0], dx);
            unsafeAtomicAdd(&sSum[cid0][1], dy);
            unsafeAtomicAdd(&sSum[cid0][2], dz);
            atomicMin(&sMin[cid0][0], encF(mnx)); atomicMin(&sMin[cid0][1], encF(mny)); atomicMin(&sMin[cid0][2], encF(mnz));
            atomicMax(&sMax[cid0][0], encF(mxx)); atomicMax(&sMax[cid0][1], encF(mxy)); atomicMax(&sMax[cid0][2], encF(mxz));
        }
    } else if (valid) {
        atomicAdd(&sCnt[cid], 1u);
        unsafeAtomicAdd(&sSum[cid][0], (double)x);
        unsafeAtomicAdd(&sSum[cid][1], (double)y);
        unsafeAtomicAdd(&sSum[cid][2], (double)z);
        atomicMin(&sMin[cid][0], encF(x)); atomicMin(&sMin[cid][1], encF(y)); atomicMin(&sMin[cid][2], encF(z));
        atomicMax(&sMax[cid][0], encF(x)); atomicMax(&sMax[cid][1], encF(y)); atomicMax(&sMax[cid][2], encF(z));
    }
    __syncthreads();
    for (int c = tid; c < NC; c += 256) {
        if (sCnt[c]) {
            atomicAdd(&gcnt[c], sCnt[c]);
            for (int d = 0; d < 3; ++d) {
                unsafeAtomicAdd(&gsum[c * 3 + d], sSum[c][d]);
                atomicMin(&gmin[c * 3 + d], sMin[c][d]);
                atomicMax(&gmax[c * 3 + d], sMax[c][d]);
            }
        }
    }
}

// ---------- kernel 2: per-cluster mean/scale/offset (double) + parallel prefix for coff ----------
__global__ void k_params(const double* gsum, const uint* gcnt, const uint* gmin,
                         const uint* gmax, double* params, int* coff) {
    __shared__ uint wsum[4];
    int c = threadIdx.x;                 // exactly 256 threads
    uint n = gcnt[c];
    double mean[3] = {0, 0, 0}, off[3] = {0, 0, 0}, scale = 50.0;
    if (n) {
        double dn = (double)n;
        double r = 0.0, mn[3];
        for (int d = 0; d < 3; ++d) {
            mean[d] = gsum[c * 3 + d] / dn;
            mn[d] = (double)decF(gmin[c * 3 + d]) - mean[d];
            double mx = (double)decF(gmax[c * 3 + d]) - mean[d];
            double ext = (mx - mn[d]) / (double)FS;
            r = fmax(r, ext);
        }
        double sr = 1.0 / r - 0.01;      // r==0 -> inf -> clamp to 50
        scale = fmin(sr, 50.0);
        for (int d = 0; d < 3; ++d) off[d] = -(mn[d] * scale);
    }
    params[c * 8 + 0] = mean[0]; params[c * 8 + 1] = mean[1]; params[c * 8 + 2] = mean[2];
    params[c * 8 + 3] = scale;
    params[c * 8 + 4] = off[0];  params[c * 8 + 5] = off[1];  params[c * 8 + 6] = off[2];
    params[c * 8 + 7] = 0.0;

    uint incl = n;
    #pragma unroll
    for (int d = 1; d < 64; d <<= 1) {
        uint y = __shfl_up(incl, d, 64);
        if ((c & 63) >= d) incl += y;
    }
    int w = c >> 6;
    if ((c & 63) == 63) wsum[w] = incl;
    __syncthreads();
    uint woff = 0;
    #pragma unroll
    for (int i = 0; i < 4; ++i) if (i < w) woff += wsum[i];
    coff[c] = (int)(incl - n + woff);
    if (c == 255) coff[NC] = (int)(incl + woff);
}

// ---------- kernel 3: per-pair local voxel id + rank + per-voxel count ----------
__global__ __launch_bounds__(256) void k_vox(const void* cids, const void* pids,
        const float* coords, const double* params,
        ushort_t* vidl, ushort_t* rankl, uint* vptr) {
    int s = blockIdx.x * blockDim.x + threadIdx.x;
    if (s >= SPAIRS) return;
    uint is64 = detect64(cids);
    int cid = loadId(cids, s, is64);
    int pid = loadId(pids, s, is64);
    const double* P = params + cid * 8;
    float cx = coords[3 * pid + 0];
    float cy = coords[3 * pid + 1];
    float cz = coords[3 * pid + 2];
    double vx = ((double)cx - P[0]) * P[3] + P[4];
    double vy = ((double)cy - P[1]) * P[3] + P[5];
    double vz = ((double)cz - P[2]) * P[3] + P[6];
    int ix = (int)floor(vx); ix = ix < 0 ? 0 : (ix > FS - 1 ? FS - 1 : ix);
    int iy = (int)floor(vy); iy = iy < 0 ? 0 : (iy > FS - 1 ? FS - 1 : iy);
    int iz = (int)floor(vz); iz = iz < 0 ? 0 : (iz > FS - 1 ? FS - 1 : iz);
    int v = (ix * FS + iy) * FS + iz;
    vidl[s] = (ushort_t)v;
    uint r = atomicAdd(&vptr[cid * F3 + v], 1u);   // rank within voxel
    rankl[s] = (ushort_t)r;
}

// ---------- kernel 4: exclusive scan of vptr + zero-fill empty & wave-split voxel rows ----------
// A voxel row is written by k_pair with a single plain store iff all its pairs sit
// inside one 64-pair wave; otherwise (split) partial sums arrive via atomicAdd and
// the row must start at zero. Empty rows are never touched by k_pair -> zero here.
__global__ __launch_bounds__(256) void k_scan(const int* coff, uint* vptr, uint* agg,
                                              float* out) {
    __shared__ uint wsum[4];
    int c = blockIdx.x, t = threadIdx.x;
    uint* base = vptr + c * F3;
    int b0 = t * 11;                 // 11*256 = 2816 >= F3
    uint cnt[11], v[11];
    uint s = 0;
    #pragma unroll
    for (int i = 0; i < 11; ++i) {
        int idx = b0 + i;
        uint x = (idx < F3) ? base[idx] : 0u;
        cnt[i] = x;
        v[i] = s;
        s += x;
    }
    uint run = s;
    #pragma unroll
    for (int d = 1; d < 64; d <<= 1) {
        uint y = __shfl_up(run, d, 64);
        if ((t & 63) >= d) run += y;
    }
    int w = t >> 6;
    if ((t & 63) == 63) wsum[w] = run;
    __syncthreads();
    uint woff = 0;
    #pragma unroll
    for (int i = 0; i < 4; ++i) if (i < w) woff += wsum[i];
    uint excl = run - s + woff + (uint)coff[c];
    #pragma unroll
    for (int i = 0; i < 11; ++i) {
        int idx = b0 + i;
        if (idx < F3) {
            uint sv = excl + v[i];
            base[idx] = sv;                          // exclusive start per voxel
            uint x = cnt[i];
            bool zero = (x == 0u) || ((sv >> 6) != ((sv + x - 1) >> 6));
            if (zero) {
                f32x4 zz = {0.f, 0.f, 0.f, 0.f};
                f32x4* o = (f32x4*)(out + (size_t)(c * F3 + idx) * 32);
                #pragma unroll
                for (int g = 0; g < 8; ++g) o[g] = zz;
            }
        }
    }
    if (c == 255 && t == 0) vptr[VOXT] = (uint)coff[NC];   // sentinel
    if (t < 32) agg[c * 32 + t] = 0u;                      // agg-enc zero
}

// ---------- kernel 5: scatter (atomic-free): spid/svid/scinv sorted by (cluster,voxel) ----------
__global__ __launch_bounds__(256) void k_scatter(const void* cids, const void* pids,
        const ushort_t* vidl, const ushort_t* rankl, const uint* vptr,
        int* spid, uint* svid, float* scinv) {
    int s = blockIdx.x * blockDim.x + threadIdx.x;
    if (s >= SPAIRS) return;
    uint is64 = detect64(cids);
    int cid = loadId(cids, s, is64);
    int pid = loadId(pids, s, is64);
    int vid = cid * F3 + (int)vidl[s];
    uint start = vptr[vid];
    uint cnt = vptr[vid + 1] - start;
    uint pos = start + (uint)rankl[s];
    spid[pos] = pid;
    svid[pos] = (uint)vid;
    scinv[pos] = 1.0f / (float)cnt;
}

// ---------- kernel 6: pair-major segmented reduce (1 pair/lane, no LDS) ----------
// Coalesced spid/svid/scinv; 8 independent dwordx4 feats loads per lane (depth-2
// chain); 6-step key-compare segmented shuffle scan sums same-voxel lanes; run
// tails plain-store finished mean rows; wave-straddling voxels atomicAdd into
// rows pre-zeroed by k_scan. Agg-max: wave butterfly + 32-lane-parallel atomicMax.
__global__ __launch_bounds__(256) void k_pair(const float4* feats4, const int* spid,
        const uint* svid, const float* scinv, float* out, uint* agg) {
    int wv = blockIdx.x * 4 + (threadIdx.x >> 6);
    int lane = threadIdx.x & 63;
    int q0 = wv * 64;
    if (q0 >= SPAIRS) return;          // whole trailing wave exits (no LDS/sync)
    int q = q0 + lane;

    int  pid = spid[q];
    uint vid = svid[q];
    float inv = scinv[q];
    uint sL = (q0 > 0) ? svid[q0 - 1] : 0xFFFFFFFFu;            // broadcast load
    uint sR = (q0 + 64 < SPAIRS) ? svid[q0 + 64] : 0xFFFFFFFFu; // broadcast load

    // segment predicates (svid non-decreasing; runs are contiguous)
    bool addm[6];
    #pragma unroll
    for (int st = 0; st < 6; ++st) {
        int d = 1 << st;
        uint vu = (uint)__shfl_up((int)vid, d, 64);
        addm[st] = (lane >= d) && (vu == vid);
    }
    uint vdn = (uint)__shfl_down((int)vid, 1, 64);
    bool tail = (lane == 63) || (vdn != vid);
    bool useAtomic = (vid == sL) || (vid == sR);   // run continues into adjacent wave

    int cid = (int)(vid / F3);
    bool uni = __all(cid == __shfl(cid, 0, 64));

    const float4* fr = feats4 + (size_t)pid * 8;
    float4 f[8];
    #pragma unroll
    for (int g = 0; g < 8; ++g) f[g] = fr[g];      // 8 independent 16B loads

    float* orow = out + (size_t)vid * 32;
    #pragma unroll
    for (int g = 0; g < 8; ++g) {
        float4 raw = f[g];
        // ---- cluster agg-max ----
        if (uni) {
            float4 m = raw;
            #pragma unroll
            for (int st = 1; st < 64; st <<= 1) {
                m.x = fmaxf(m.x, __shfl_xor(m.x, st, 64));
                m.y = fmaxf(m.y, __shfl_xor(m.y, st, 64));
                m.z = fmaxf(m.z, __shfl_xor(m.z, st, 64));
                m.w = fmaxf(m.w, __shfl_xor(m.w, st, 64));
            }
            if ((lane >> 2) == g) {                // lanes 4g..4g+3, one atomic each
                int j = lane & 3;
                float vmax = (j == 0) ? m.x : (j == 1) ? m.y : (j == 2) ? m.z : m.w;
                atomicMax(&agg[cid * 32 + g * 4 + j], encF(vmax));
            }
        } else {                                    // cluster-boundary wave (rare)
            atomicMax(&agg[cid * 32 + g * 4 + 0], encF(raw.x));
            atomicMax(&agg[cid * 32 + g * 4 + 1], encF(raw.y));
            atomicMax(&agg[cid * 32 + g * 4 + 2], encF(raw.z));
            atomicMax(&agg[cid * 32 + g * 4 + 3], encF(raw.w));
        }
        // ---- segmented mean-sum ----
        float4 x;
        x.x = raw.x * inv; x.y = raw.y * inv; x.z = raw.z * inv; x.w = raw.w * inv;
        #pragma unroll
        for (int st = 0; st < 6; ++st) {
            int d = 1 << st;
            float tx = __shfl_up(x.x, d, 64);
            float ty = __shfl_up(x.y, d, 64);
            float tz = __shfl_up(x.z, d, 64);
            float tw = __shfl_up(x.w, d, 64);
            if (addm[st]) { x.x += tx; x.y += ty; x.z += tz; x.w += tw; }
        }
        if (tail) {
            if (useAtomic) {
                unsafeAtomicAdd(orow + g * 4 + 0, x.x);
                unsafeAtomicAdd(orow + g * 4 + 1, x.y);
                unsafeAtomicAdd(orow + g * 4 + 2, x.z);
                unsafeAtomicAdd(orow + g * 4 + 3, x.w);
            } else {
                f32x4 xs = {x.x, x.y, x.z, x.w};
                *(f32x4*)(orow + g * 4) = xs;
            }
        }
    }
}

// ---------- kernel 7: agg finalize (decode; untouched/neginf -> 0) ----------
__global__ void k_aggfin(float* outbase) {
    int i = blockIdx.x * blockDim.x + threadIdx.x;     // < NC*32 exactly
    uint* a = (uint*)(outbase + (size_t)VOXT * 32);
    uint e = a[i];
    float f = decF(e);
    if (e == 0u || f == -INFINITY) f = 0.0f;
    ((float*)a)[i] = f;
}

extern "C" void kernel_launch(void* const* d_in, const int* in_sizes, int n_in,
                              void* d_out, int out_size, void* d_ws, size_t ws_size,
                              hipStream_t stream) {
    const float* feats  = (const float*)d_in[0];
    const float* coords = (const float*)d_in[1];
    const void*  cids   = d_in[2];
    const void*  pids   = d_in[3];
    float* out = (float*)d_out;
    char* ws = (char*)d_ws;

    // ws layout (bytes):
    //   0         double gsum[256*3]       (6144)    } zero
    //   6144      uint   gcnt[256]         (1024)    } zero
    //   7168      uint   gmax[256*3]       (3072)    } zero
    //   10240     uint   vptr[VOXT+1]      (2809860) } zero  -> pad 2820160
    //   2820160   uint   gmin[256*3]       (3072)    0xFF
    //   2823232   double params[256*8]     (16384)
    //   2839616   int    coff[257]         (1028 -> pad 2840704)
    //   2840704   u16    vidl[SPAIRS]      (1200000) -> 4040704
    //   4040704   u16    rankl[SPAIRS]     (1200000) -> 5240704
    //   5240704   int    spid[SPAIRS]      (2400000) -> 7640704
    //   7640704   uint   svid[SPAIRS]      (2400000) -> 10040704
    //   10040704  float  scinv[SPAIRS]     (2400000) -> 12440704
    double*   gsum   = (double*)(ws + 0);
    uint*     gcnt   = (uint*)(ws + 6144);
    uint*     gmax   = (uint*)(ws + 7168);
    uint*     vptr   = (uint*)(ws + 10240);
    uint*     gmin   = (uint*)(ws + 2820160);
    double*   params = (double*)(ws + 2823232);
    int*      coff   = (int*)(ws + 2839616);
    ushort_t* vidl   = (ushort_t*)(ws + 2840704);
    ushort_t* rankl  = (ushort_t*)(ws + 4040704);
    int*      spid   = (int*)(ws + 5240704);
    uint*     svid   = (uint*)(ws + 7640704);
    float*    scinv  = (float*)(ws + 10040704);
    uint*     agg    = (uint*)(out + (size_t)VOXT * 32);

    hipMemsetAsync(ws, 0, 2820160, stream);               // gsum..vptr(+sentinel)
    hipMemsetAsync((void*)gmin, 0xFF, 3072, stream);      // gmin = +max encodings

    int nb = (SPAIRS + 255) / 256;   // 2344
    k_stats<<<nb, 256, 0, stream>>>(cids, pids, coords, gsum, gcnt, gmin, gmax);
    k_params<<<1, 256, 0, stream>>>(gsum, gcnt, gmin, gmax, params, coff);
    k_vox<<<nb, 256, 0, stream>>>(cids, pids, coords, params, vidl, rankl, vptr);
    k_scan<<<NC, 256, 0, stream>>>(coff, vptr, agg, out);
    k_scatter<<<nb, 256, 0, stream>>>(cids, pids, vidl, rankl, vptr, spid, svid, scinv);
    k_pair<<<nb, 256, 0, stream>>>((const float4*)feats, spid, svid, scinv, out, agg);
    k_aggfin<<<(NC * 32) / 256, 256, 0, stream>>>(out);
}

// Round 7
// 123.816 us; speedup vs baseline: 1.8573x; 1.8573x over previous
//
#include <hip/hip_runtime.h>
#include <stdint.h>

typedef unsigned int uint;
typedef unsigned short ushort_t;

#define NPTS 500000
#define NC 256
#define SPAIRS 600000
#define FS 14
#define F3 2744            // 14^3
#define VOXT (NC * F3)     // 702464
#define STRIP 343          // F3/8 voxels per k_out block

// ---------- helpers ----------
__device__ __forceinline__ uint encF(float f) {
    uint u = __float_as_uint(f);
    return (u & 0x80000000u) ? ~u : (u | 0x80000000u);
}
__device__ __forceinline__ float decF(uint e) {
    uint u = (e & 0x80000000u) ? (e ^ 0x80000000u) : ~e;
    return __uint_as_float(u);
}
// ids may arrive as int32 (jax x64 off) or int64. Sorted cids: mid values ~128,
// so for int64 the odd int32 words (high) are 0; for int32 they're nonzero.
__device__ __forceinline__ uint detect64(const void* cids) {
    const int* p = (const int*)cids;
    int z = 0;
    #pragma unroll
    for (int k = 0; k < 5; ++k) z += (p[300001 + 2 * k] == 0) ? 1 : 0;
    return (z >= 3) ? 1u : 0u;
}
__device__ __forceinline__ int loadId(const void* p, int i, uint is64) {
    return is64 ? (int)((const long long*)p)[i] : ((const int*)p)[i];
}

// ---------- kernel 1: per-cluster count/sum(f64)/min/max + cache gathered coords ----------
__global__ __launch_bounds__(256) void k_stats(const void* cids, const void* pids,
        const float* __restrict__ coords,
        double* gsum, uint* gcnt, uint* gmin, uint* gmax, float* __restrict__ ccoord) {
    __shared__ double sSum[NC][3];
    __shared__ uint   sCnt[NC];
    __shared__ uint   sMin[NC][3];
    __shared__ uint   sMax[NC][3];
    int tid = threadIdx.x;
    for (int c = tid; c < NC; c += 256) {
        sCnt[c] = 0u;
        for (int d = 0; d < 3; ++d) { sSum[c][d] = 0.0; sMin[c][d] = 0xFFFFFFFFu; sMax[c][d] = 0u; }
    }
    __syncthreads();
    uint is64 = detect64(cids);
    int s = blockIdx.x * 256 + tid;
    bool valid = s < SPAIRS;
    int sc = valid ? s : SPAIRS - 1;
    int cid = loadId(cids, sc, is64);
    int pid = loadId(pids, sc, is64);
    float x = coords[3 * pid + 0];
    float y = coords[3 * pid + 1];
    float z = coords[3 * pid + 2];
    if (valid) {               // cache gathered coords contiguously for k_vox
        ccoord[3 * s + 0] = x;
        ccoord[3 * s + 1] = y;
        ccoord[3 * s + 2] = z;
    }
    int lane = tid & 63;
    int cid0 = __shfl(cid, 0, 64), cid63 = __shfl(cid, 63, 64);
    if (cid0 == cid63) {
        uint nval = (uint)__popcll(__ballot(valid));
        double dx = valid ? (double)x : 0.0;
        double dy = valid ? (double)y : 0.0;
        double dz = valid ? (double)z : 0.0;
        float mnx = valid ? x : INFINITY,  mny = valid ? y : INFINITY,  mnz = valid ? z : INFINITY;
        float mxx = valid ? x : -INFINITY, mxy = valid ? y : -INFINITY, mxz = valid ? z : -INFINITY;
        #pragma unroll
        for (int st = 1; st < 64; st <<= 1) {
            dx += __shfl_xor(dx, st, 64);
            dy += __shfl_xor(dy, st, 64);
            dz += __shfl_xor(dz, st, 64);
            mnx = fminf(mnx, __shfl_xor(mnx, st, 64));
            mny = fminf(mny, __shfl_xor(mny, st, 64));
            mnz = fminf(mnz, __shfl_xor(mnz, st, 64));
            mxx = fmaxf(mxx, __shfl_xor(mxx, st, 64));
            mxy = fmaxf(mxy, __shfl_xor(mxy, st, 64));
            mxz = fmaxf(mxz, __shfl_xor(mxz, st, 64));
        }
        if (lane == 0 && nval) {
            atomicAdd(&sCnt[cid0], nval);
            unsafeAtomicAdd(&sSum[cid0][0], dx);
            unsafeAtomicAdd(&sSum[cid0][1], dy);
            unsafeAtomicAdd(&sSum[cid0][2], dz);
            atomicMin(&sMin[cid0][0], encF(mnx)); atomicMin(&sMin[cid0][1], encF(mny)); atomicMin(&sMin[cid0][2], encF(mnz));
            atomicMax(&sMax[cid0][0], encF(mxx)); atomicMax(&sMax[cid0][1], encF(mxy)); atomicMax(&sMax[cid0][2], encF(mxz));
        }
    } else if (valid) {
        atomicAdd(&sCnt[cid], 1u);
        unsafeAtomicAdd(&sSum[cid][0], (double)x);
        unsafeAtomicAdd(&sSum[cid][1], (double)y);
        unsafeAtomicAdd(&sSum[cid][2], (double)z);
        atomicMin(&sMin[cid][0], encF(x)); atomicMin(&sMin[cid][1], encF(y)); atomicMin(&sMin[cid][2], encF(z));
        atomicMax(&sMax[cid][0], encF(x)); atomicMax(&sMax[cid][1], encF(y)); atomicMax(&sMax[cid][2], encF(z));
    }
    __syncthreads();
    for (int c = tid; c < NC; c += 256) {
        if (sCnt[c]) {
            atomicAdd(&gcnt[c], sCnt[c]);
            for (int d = 0; d < 3; ++d) {
                unsafeAtomicAdd(&gsum[c * 3 + d], sSum[c][d]);
                atomicMin(&gmin[c * 3 + d], sMin[c][d]);
                atomicMax(&gmax[c * 3 + d], sMax[c][d]);
            }
        }
    }
}

// ---------- kernel 2: per-cluster mean/scale/offset (double) + parallel prefix for coff ----------
__global__ void k_params(const double* gsum, const uint* gcnt, const uint* gmin,
                         const uint* gmax, double* params, int* coff) {
    __shared__ uint wsum[4];
    int c = threadIdx.x;                 // exactly 256 threads
    uint n = gcnt[c];
    double mean[3] = {0, 0, 0}, off[3] = {0, 0, 0}, scale = 50.0;
    if (n) {
        double dn = (double)n;
        double r = 0.0, mn[3];
        for (int d = 0; d < 3; ++d) {
            mean[d] = gsum[c * 3 + d] / dn;
            mn[d] = (double)decF(gmin[c * 3 + d]) - mean[d];
            double mx = (double)decF(gmax[c * 3 + d]) - mean[d];
            double ext = (mx - mn[d]) / (double)FS;
            r = fmax(r, ext);
        }
        double sr = 1.0 / r - 0.01;      // r==0 -> inf -> clamp to 50
        scale = fmin(sr, 50.0);
        for (int d = 0; d < 3; ++d) off[d] = -(mn[d] * scale);
    }
    params[c * 8 + 0] = mean[0]; params[c * 8 + 1] = mean[1]; params[c * 8 + 2] = mean[2];
    params[c * 8 + 3] = scale;
    params[c * 8 + 4] = off[0];  params[c * 8 + 5] = off[1];  params[c * 8 + 6] = off[2];
    params[c * 8 + 7] = 0.0;

    uint incl = n;
    #pragma unroll
    for (int d = 1; d < 64; d <<= 1) {
        uint y = __shfl_up(incl, d, 64);
        if ((c & 63) >= d) incl += y;
    }
    int w = c >> 6;
    if ((c & 63) == 63) wsum[w] = incl;
    __syncthreads();
    uint woff = 0;
    #pragma unroll
    for (int i = 0; i < 4; ++i) if (i < w) woff += wsum[i];
    coff[c] = (int)(incl - n + woff);
    if (c == 255) coff[NC] = (int)(incl + woff);
}

// ---------- kernel 3: voxel id + rank + per-voxel count (fully coalesced reads) ----------
__global__ __launch_bounds__(256) void k_vox(const void* cids,
        const float* __restrict__ ccoord, const double* __restrict__ params,
        ushort_t* vidl, ushort_t* rankl, uint* vptr) {
    int s = blockIdx.x * blockDim.x + threadIdx.x;
    if (s >= SPAIRS) return;
    uint is64 = detect64(cids);
    int cid = loadId(cids, s, is64);
    const double* P = params + cid * 8;
    float cx = ccoord[3 * s + 0];
    float cy = ccoord[3 * s + 1];
    float cz = ccoord[3 * s + 2];
    double vx = ((double)cx - P[0]) * P[3] + P[4];
    double vy = ((double)cy - P[1]) * P[3] + P[5];
    double vz = ((double)cz - P[2]) * P[3] + P[6];
    int ix = (int)floor(vx); ix = ix < 0 ? 0 : (ix > FS - 1 ? FS - 1 : ix);
    int iy = (int)floor(vy); iy = iy < 0 ? 0 : (iy > FS - 1 ? FS - 1 : iy);
    int iz = (int)floor(vz); iz = iz < 0 ? 0 : (iz > FS - 1 ? FS - 1 : iz);
    int v = (ix * FS + iy) * FS + iz;
    vidl[s] = (ushort_t)v;
    uint r = atomicAdd(&vptr[cid * F3 + v], 1u);   // rank within voxel
    rankl[s] = (ushort_t)r;
}

// ---------- kernel 4: per-cluster exclusive scan of vptr (+coff base) + sentinel + agg zero ----------
__global__ __launch_bounds__(256) void k_scan(const int* coff, uint* vptr, uint* agg) {
    __shared__ uint wsum[4];
    int c = blockIdx.x, t = threadIdx.x;
    uint* base = vptr + c * F3;
    int b0 = t * 11;                 // 11*256 = 2816 >= F3
    uint v[11];
    uint s = 0;
    #pragma unroll
    for (int i = 0; i < 11; ++i) {
        int idx = b0 + i;
        uint x = (idx < F3) ? base[idx] : 0u;
        v[i] = s;
        s += x;
    }
    uint run = s;
    #pragma unroll
    for (int d = 1; d < 64; d <<= 1) {
        uint y = __shfl_up(run, d, 64);
        if ((t & 63) >= d) run += y;
    }
    int w = t >> 6;
    if ((t & 63) == 63) wsum[w] = run;
    __syncthreads();
    uint woff = 0;
    #pragma unroll
    for (int i = 0; i < 4; ++i) if (i < w) woff += wsum[i];
    uint excl = run - s + woff + (uint)coff[c];
    #pragma unroll
    for (int i = 0; i < 11; ++i) {
        int idx = b0 + i;
        if (idx < F3) base[idx] = excl + v[i];   // exclusive start per voxel
    }
    if (c == 255 && t == 0) vptr[VOXT] = (uint)coff[NC];   // sentinel
    if (t < 32) agg[c * 32 + t] = 0u;                      // agg-enc zero
}

// ---------- kernel 5: deterministic scatter: spid = pair pids sorted by (cluster,voxel) ----------
__global__ __launch_bounds__(256) void k_scatter(const void* cids, const void* pids,
        const ushort_t* vidl, const ushort_t* rankl, const uint* vptr, int* spid) {
    int s = blockIdx.x * blockDim.x + threadIdx.x;
    if (s >= SPAIRS) return;
    uint is64 = detect64(cids);
    int cid = loadId(cids, s, is64);
    int pid = loadId(pids, s, is64);
    int vid = cid * F3 + (int)vidl[s];
    uint pos = vptr[vid] + (uint)rankl[s];
    spid[pos] = pid;
}

// ---------- kernel 6: channel-parallel voxel mean + agg max ----------
// 32 lanes = 32 channels own one voxel. spid[q] = same-address broadcast (1 line);
// feats row = one 128B line per group; out row = one 128B line per group. All hot
// loads are 1-2 cache lines per instruction (vs 64 divergent rows before).
__global__ __launch_bounds__(256) void k_out(const float* __restrict__ feats,
        const uint* __restrict__ vptr, const int* __restrict__ spid,
        float* __restrict__ out, uint* __restrict__ agg) {
    __shared__ uint  sVptr[344];
    __shared__ float sMx[8][32];
    int b = blockIdx.x;
    int xcd = b & 7, r = b >> 3;
    int c = xcd * 32 + (r >> 3);     // cluster (XCD-swizzled)
    int p = r & 7;                   // eighth
    int t = threadIdx.x;
    int vid0 = c * F3 + p * STRIP;

    sVptr[t] = vptr[vid0 + t];
    if (t < 88) sVptr[256 + t] = vptr[vid0 + 256 + t];
    __syncthreads();

    int gi = t >> 5;                 // voxel-group 0..7
    int ch = t & 31;                 // channel 0..31
    float mx = -INFINITY;

    #pragma unroll 2
    for (int j = 0; j < 43; ++j) {
        int v = gi + 8 * j;          // strided ownership (load balance)
        if (v < STRIP) {
            uint s0 = sVptr[v], s1 = sVptr[v + 1];
            uint cnt = s1 - s0;
            float acc = 0.f;
            if (cnt >= 1) {                       // two independent head loads
                int p0 = spid[s0];
                float f0 = feats[(size_t)p0 * 32 + ch];
                acc = f0; mx = fmaxf(mx, f0);
            }
            if (cnt >= 2) {
                int p1 = spid[s0 + 1];
                float f1 = feats[(size_t)p1 * 32 + ch];
                acc += f1; mx = fmaxf(mx, f1);
            }
            for (uint q = s0 + 2; q < s1; ++q) {  // rare tail (P(cnt>2) ~ 5%)
                int pq = spid[q];
                float fq = feats[(size_t)pq * 32 + ch];
                acc += fq; mx = fmaxf(mx, fq);
            }
            float fcnt = cnt ? (float)cnt : 1.0f;
            float inv = __builtin_amdgcn_rcpf(fcnt);
            out[(size_t)(vid0 + v) * 32 + ch] = acc * inv;
        }
    }

    sMx[gi][ch] = mx;
    __syncthreads();
    if (t < 32) {
        float m = sMx[0][t];
        #pragma unroll
        for (int g = 1; g < 8; ++g) m = fmaxf(m, sMx[g][t]);
        if (m != -INFINITY) atomicMax(&agg[c * 32 + t], encF(m));
    }
}

// ---------- kernel 7: agg finalize (decode; untouched/neginf -> 0) ----------
__global__ void k_aggfin(float* outbase) {
    int i = blockIdx.x * blockDim.x + threadIdx.x;     // < NC*32 exactly
    uint* a = (uint*)(outbase + (size_t)VOXT * 32);
    uint e = a[i];
    float f = decF(e);
    if (e == 0u || f == -INFINITY) f = 0.0f;
    ((float*)a)[i] = f;
}

extern "C" void kernel_launch(void* const* d_in, const int* in_sizes, int n_in,
                              void* d_out, int out_size, void* d_ws, size_t ws_size,
                              hipStream_t stream) {
    const float* feats  = (const float*)d_in[0];
    const float* coords = (const float*)d_in[1];
    const void*  cids   = d_in[2];
    const void*  pids   = d_in[3];
    float* out = (float*)d_out;
    char* ws = (char*)d_ws;

    // ws layout (bytes), total 12,440,704 (same footprint as round 6):
    //   0         double gsum[256*3]       (6144)    } zero
    //   6144      uint   gcnt[256]         (1024)    } zero
    //   7168      uint   gmax[256*3]       (3072)    } zero
    //   10240     uint   vptr[VOXT+1]      (2809860) } zero  -> pad 2820160
    //   2820160   uint   gmin[256*3]       (3072)    0xFF
    //   2823232   double params[256*8]     (16384)
    //   2839616   int    coff[257]         (1028 -> pad 2840704)
    //   2840704   u16    vidl[SPAIRS]      (1200000) -> 4040704
    //   4040704   u16    rankl[SPAIRS]     (1200000) -> 5240704
    //   5240704   float  ccoord[3*SPAIRS]  (7200000) -> 12440704
    //             int    spid[SPAIRS]      (2400000) ALIASES ccoord (dead after k_vox)
    double*   gsum   = (double*)(ws + 0);
    uint*     gcnt   = (uint*)(ws + 6144);
    uint*     gmax   = (uint*)(ws + 7168);
    uint*     vptr   = (uint*)(ws + 10240);
    uint*     gmin   = (uint*)(ws + 2820160);
    double*   params = (double*)(ws + 2823232);
    int*      coff   = (int*)(ws + 2839616);
    ushort_t* vidl   = (ushort_t*)(ws + 2840704);
    ushort_t* rankl  = (ushort_t*)(ws + 4040704);
    float*    ccoord = (float*)(ws + 5240704);
    int*      spid   = (int*)(ws + 5240704);     // alias: ccoord dead before k_scatter
    uint*     agg    = (uint*)(out + (size_t)VOXT * 32);

    hipMemsetAsync(ws, 0, 2820160, stream);               // gsum..vptr(+sentinel)
    hipMemsetAsync((void*)gmin, 0xFF, 3072, stream);      // gmin = +max encodings

    int nb = (SPAIRS + 255) / 256;   // 2344
    k_stats<<<nb, 256, 0, stream>>>(cids, pids, coords, gsum, gcnt, gmin, gmax, ccoord);
    k_params<<<1, 256, 0, stream>>>(gsum, gcnt, gmin, gmax, params, coff);
    k_vox<<<nb, 256, 0, stream>>>(cids, ccoord, params, vidl, rankl, vptr);
    k_scan<<<NC, 256, 0, stream>>>(coff, vptr, agg);
    k_scatter<<<nb, 256, 0, stream>>>(cids, pids, vidl, rankl, vptr, spid);
    k_out<<<NC * 8, 256, 0, stream>>>(feats, vptr, spid, out, agg);
    k_aggfin<<<(NC * 32) / 256, 256, 0, stream>>>(out);
}

// Round 8
// 114.215 us; speedup vs baseline: 2.0134x; 1.0841x over previous
//
#include <hip/hip_runtime.h>
#include <stdint.h>

typedef unsigned int uint;
typedef unsigned short ushort_t;

#define NPTS 500000
#define NC 256
#define SPAIRS 600000
#define FS 14
#define F3 2744            // 14^3
#define VOXT (NC * F3)     // 702464
#define STRIP 343          // F3/8 voxels per k_out block
#define PCAP 3072          // LDS pid-stage capacity (max pairs/strip ~2.6K)

// ---------- helpers ----------
__device__ __forceinline__ uint encF(float f) {
    uint u = __float_as_uint(f);
    return (u & 0x80000000u) ? ~u : (u | 0x80000000u);
}
__device__ __forceinline__ float decF(uint e) {
    uint u = (e & 0x80000000u) ? (e ^ 0x80000000u) : ~e;
    return __uint_as_float(u);
}
// ids may arrive as int32 (jax x64 off) or int64. Sorted cids: mid values ~128,
// so for int64 the odd int32 words (high) are 0; for int32 they're nonzero.
__device__ __forceinline__ uint detect64(const void* cids) {
    const int* p = (const int*)cids;
    int z = 0;
    #pragma unroll
    for (int k = 0; k < 5; ++k) z += (p[300001 + 2 * k] == 0) ? 1 : 0;
    return (z >= 3) ? 1u : 0u;
}
__device__ __forceinline__ int loadId(const void* p, int i, uint is64) {
    return is64 ? (int)((const long long*)p)[i] : ((const int*)p)[i];
}

// ---------- kernel 1: per-cluster count/sum(f64)/min/max + cache gathered coords ----------
__global__ __launch_bounds__(256) void k_stats(const void* cids, const void* pids,
        const float* __restrict__ coords,
        double* gsum, uint* gcnt, uint* gmin, uint* gmax, float* __restrict__ ccoord) {
    __shared__ double sSum[NC][3];
    __shared__ uint   sCnt[NC];
    __shared__ uint   sMin[NC][3];
    __shared__ uint   sMax[NC][3];
    int tid = threadIdx.x;
    for (int c = tid; c < NC; c += 256) {
        sCnt[c] = 0u;
        for (int d = 0; d < 3; ++d) { sSum[c][d] = 0.0; sMin[c][d] = 0xFFFFFFFFu; sMax[c][d] = 0u; }
    }
    __syncthreads();
    uint is64 = detect64(cids);
    int s = blockIdx.x * 256 + tid;
    bool valid = s < SPAIRS;
    int sc = valid ? s : SPAIRS - 1;
    int cid = loadId(cids, sc, is64);
    int pid = loadId(pids, sc, is64);
    float x = coords[3 * pid + 0];
    float y = coords[3 * pid + 1];
    float z = coords[3 * pid + 2];
    if (valid) {               // cache gathered coords contiguously for k_vox
        ccoord[3 * s + 0] = x;
        ccoord[3 * s + 1] = y;
        ccoord[3 * s + 2] = z;
    }
    int lane = tid & 63;
    int cid0 = __shfl(cid, 0, 64), cid63 = __shfl(cid, 63, 64);
    if (cid0 == cid63) {
        uint nval = (uint)__popcll(__ballot(valid));
        double dx = valid ? (double)x : 0.0;
        double dy = valid ? (double)y : 0.0;
        double dz = valid ? (double)z : 0.0;
        float mnx = valid ? x : INFINITY,  mny = valid ? y : INFINITY,  mnz = valid ? z : INFINITY;
        float mxx = valid ? x : -INFINITY, mxy = valid ? y : -INFINITY, mxz = valid ? z : -INFINITY;
        #pragma unroll
        for (int st = 1; st < 64; st <<= 1) {
            dx += __shfl_xor(dx, st, 64);
            dy += __shfl_xor(dy, st, 64);
            dz += __shfl_xor(dz, st, 64);
            mnx = fminf(mnx, __shfl_xor(mnx, st, 64));
            mny = fminf(mny, __shfl_xor(mny, st, 64));
            mnz = fminf(mnz, __shfl_xor(mnz, st, 64));
            mxx = fmaxf(mxx, __shfl_xor(mxx, st, 64));
            mxy = fmaxf(mxy, __shfl_xor(mxy, st, 64));
            mxz = fmaxf(mxz, __shfl_xor(mxz, st, 64));
        }
        if (lane == 0 && nval) {
            atomicAdd(&sCnt[cid0], nval);
            unsafeAtomicAdd(&sSum[cid0][0], dx);
            unsafeAtomicAdd(&sSum[cid0][1], dy);
            unsafeAtomicAdd(&sSum[cid0][2], dz);
            atomicMin(&sMin[cid0][0], encF(mnx)); atomicMin(&sMin[cid0][1], encF(mny)); atomicMin(&sMin[cid0][2], encF(mnz));
            atomicMax(&sMax[cid0][0], encF(mxx)); atomicMax(&sMax[cid0][1], encF(mxy)); atomicMax(&sMax[cid0][2], encF(mxz));
        }
    } else if (valid) {
        atomicAdd(&sCnt[cid], 1u);
        unsafeAtomicAdd(&sSum[cid][0], (double)x);
        unsafeAtomicAdd(&sSum[cid][1], (double)y);
        unsafeAtomicAdd(&sSum[cid][2], (double)z);
        atomicMin(&sMin[cid][0], encF(x)); atomicMin(&sMin[cid][1], encF(y)); atomicMin(&sMin[cid][2], encF(z));
        atomicMax(&sMax[cid][0], encF(x)); atomicMax(&sMax[cid][1], encF(y)); atomicMax(&sMax[cid][2], encF(z));
    }
    __syncthreads();
    for (int c = tid; c < NC; c += 256) {
        if (sCnt[c]) {
            atomicAdd(&gcnt[c], sCnt[c]);
            for (int d = 0; d < 3; ++d) {
                unsafeAtomicAdd(&gsum[c * 3 + d], sSum[c][d]);
                atomicMin(&gmin[c * 3 + d], sMin[c][d]);
                atomicMax(&gmax[c * 3 + d], sMax[c][d]);
            }
        }
    }
}

// ---------- kernel 2: per-cluster mean/scale/offset (double) + parallel prefix for coff ----------
__global__ void k_params(const double* gsum, const uint* gcnt, const uint* gmin,
                         const uint* gmax, double* params, int* coff) {
    __shared__ uint wsum[4];
    int c = threadIdx.x;                 // exactly 256 threads
    uint n = gcnt[c];
    double mean[3] = {0, 0, 0}, off[3] = {0, 0, 0}, scale = 50.0;
    if (n) {
        double dn = (double)n;
        double r = 0.0, mn[3];
        for (int d = 0; d < 3; ++d) {
            mean[d] = gsum[c * 3 + d] / dn;
            mn[d] = (double)decF(gmin[c * 3 + d]) - mean[d];
            double mx = (double)decF(gmax[c * 3 + d]) - mean[d];
            double ext = (mx - mn[d]) / (double)FS;
            r = fmax(r, ext);
        }
        double sr = 1.0 / r - 0.01;      // r==0 -> inf -> clamp to 50
        scale = fmin(sr, 50.0);
        for (int d = 0; d < 3; ++d) off[d] = -(mn[d] * scale);
    }
    params[c * 8 + 0] = mean[0]; params[c * 8 + 1] = mean[1]; params[c * 8 + 2] = mean[2];
    params[c * 8 + 3] = scale;
    params[c * 8 + 4] = off[0];  params[c * 8 + 5] = off[1];  params[c * 8 + 6] = off[2];
    params[c * 8 + 7] = 0.0;

    uint incl = n;
    #pragma unroll
    for (int d = 1; d < 64; d <<= 1) {
        uint y = __shfl_up(incl, d, 64);
        if ((c & 63) >= d) incl += y;
    }
    int w = c >> 6;
    if ((c & 63) == 63) wsum[w] = incl;
    __syncthreads();
    uint woff = 0;
    #pragma unroll
    for (int i = 0; i < 4; ++i) if (i < w) woff += wsum[i];
    coff[c] = (int)(incl - n + woff);
    if (c == 255) coff[NC] = (int)(incl + woff);
}

// ---------- kernel 3: voxel id + rank + per-voxel count (fully coalesced reads) ----------
__global__ __launch_bounds__(256) void k_vox(const void* cids,
        const float* __restrict__ ccoord, const double* __restrict__ params,
        ushort_t* vidl, ushort_t* rankl, uint* vptr) {
    int s = blockIdx.x * blockDim.x + threadIdx.x;
    if (s >= SPAIRS) return;
    uint is64 = detect64(cids);
    int cid = loadId(cids, s, is64);
    const double* P = params + cid * 8;
    float cx = ccoord[3 * s + 0];
    float cy = ccoord[3 * s + 1];
    float cz = ccoord[3 * s + 2];
    double vx = ((double)cx - P[0]) * P[3] + P[4];
    double vy = ((double)cy - P[1]) * P[3] + P[5];
    double vz = ((double)cz - P[2]) * P[3] + P[6];
    int ix = (int)floor(vx); ix = ix < 0 ? 0 : (ix > FS - 1 ? FS - 1 : ix);
    int iy = (int)floor(vy); iy = iy < 0 ? 0 : (iy > FS - 1 ? FS - 1 : iy);
    int iz = (int)floor(vz); iz = iz < 0 ? 0 : (iz > FS - 1 ? FS - 1 : iz);
    int v = (ix * FS + iy) * FS + iz;
    vidl[s] = (ushort_t)v;
    uint r = atomicAdd(&vptr[cid * F3 + v], 1u);   // rank within voxel
    rankl[s] = (ushort_t)r;
}

// ---------- kernel 4: per-cluster exclusive scan of vptr (+coff base) + sentinel + agg zero ----------
__global__ __launch_bounds__(256) void k_scan(const int* coff, uint* vptr, uint* agg) {
    __shared__ uint wsum[4];
    int c = blockIdx.x, t = threadIdx.x;
    uint* base = vptr + c * F3;
    int b0 = t * 11;                 // 11*256 = 2816 >= F3
    uint v[11];
    uint s = 0;
    #pragma unroll
    for (int i = 0; i < 11; ++i) {
        int idx = b0 + i;
        uint x = (idx < F3) ? base[idx] : 0u;
        v[i] = s;
        s += x;
    }
    uint run = s;
    #pragma unroll
    for (int d = 1; d < 64; d <<= 1) {
        uint y = __shfl_up(run, d, 64);
        if ((t & 63) >= d) run += y;
    }
    int w = t >> 6;
    if ((t & 63) == 63) wsum[w] = run;
    __syncthreads();
    uint woff = 0;
    #pragma unroll
    for (int i = 0; i < 4; ++i) if (i < w) woff += wsum[i];
    uint excl = run - s + woff + (uint)coff[c];
    #pragma unroll
    for (int i = 0; i < 11; ++i) {
        int idx = b0 + i;
        if (idx < F3) base[idx] = excl + v[i];   // exclusive start per voxel
    }
    if (c == 255 && t == 0) vptr[VOXT] = (uint)coff[NC];   // sentinel
    if (t < 32) agg[c * 32 + t] = 0u;                      // agg-enc zero
}

// ---------- kernel 5: deterministic scatter: spid = pair pids sorted by (cluster,voxel) ----------
__global__ __launch_bounds__(256) void k_scatter(const void* cids, const void* pids,
        const ushort_t* vidl, const ushort_t* rankl, const uint* vptr, int* spid) {
    int s = blockIdx.x * blockDim.x + threadIdx.x;
    if (s >= SPAIRS) return;
    uint is64 = detect64(cids);
    int cid = loadId(cids, s, is64);
    int pid = loadId(pids, s, is64);
    int vid = cid * F3 + (int)vidl[s];
    uint pos = vptr[vid] + (uint)rankl[s];
    spid[pos] = pid;
}

// ---------- kernel 6: channel-parallel voxel mean + agg max, LDS-staged pids ----------
// 32 lanes = 32 channels own one voxel. The strip's spid slice (~293 ints) is
// contiguous -> staged to LDS, so the only global dependent load is feats itself
// (depth-1 chain). 4-voxel batches issue 8 independent feats-row loads per wave
// (select-clamped, unconditional) -> high MLP with clean 128B-line coalescing.
__global__ __launch_bounds__(256) void k_out(const float* __restrict__ feats,
        const uint* __restrict__ vptr, const int* __restrict__ spid,
        float* __restrict__ out, uint* __restrict__ agg) {
    __shared__ uint  sVptr[344];
    __shared__ int   sPid[PCAP];
    __shared__ float sMx[8][32];
    int b = blockIdx.x;
    int xcd = b & 7, r = b >> 3;
    int c = xcd * 32 + (r >> 3);     // cluster (XCD-swizzled)
    int p = r & 7;                   // eighth
    int t = threadIdx.x;
    int vid0 = c * F3 + p * STRIP;

    sVptr[t] = vptr[vid0 + t];
    if (t < 88) sVptr[256 + t] = vptr[vid0 + 256 + t];
    __syncthreads();
    uint S0 = sVptr[0], S1 = sVptr[343];
    int np = (int)(S1 - S0);
    bool fits = np <= PCAP;
    if (t == 0) sPid[0] = 0;                     // np==0 safety (overwritten below)
    if (fits) for (int i = t; i < np; i += 256) sPid[i] = spid[S0 + i];
    __syncthreads();

    int gi = t >> 5;                 // voxel-slot 0..7
    int ch = t & 31;                 // channel 0..31
    float mx = -INFINITY;

    for (int jb = 0; jb < 11; ++jb) {
        int vb = gi + 32 * jb;       // voxels vb + 8m, m=0..3
        uint s0[4], cn[4];
        int pid0[4], pid1[4];
        #pragma unroll
        for (int m = 0; m < 4; ++m) {
            int v = vb + 8 * m;
            bool ok = v < STRIP;
            int vc = ok ? v : 342;
            s0[m] = sVptr[vc];
            cn[m] = ok ? (sVptr[vc + 1] - s0[m]) : 0u;
            uint i0 = s0[m] - S0;
            uint i0c = (cn[m] >= 1) ? i0 : 0u;           // clamp: empty -> idx 0
            uint i1c = (cn[m] >= 2) ? (i0 + 1) : i0c;    // clamp: dup head line
            pid0[m] = fits ? sPid[i0c] : spid[S0 + i0c];
            pid1[m] = fits ? sPid[i1c] : spid[S0 + i1c];
        }
        float f0[4], f1[4];
        #pragma unroll
        for (int m = 0; m < 4; ++m) f0[m] = feats[(size_t)pid0[m] * 32 + ch];
        #pragma unroll
        for (int m = 0; m < 4; ++m) f1[m] = feats[(size_t)pid1[m] * 32 + ch];
        float a[4];
        #pragma unroll
        for (int m = 0; m < 4; ++m) {
            float t0 = (cn[m] >= 1) ? f0[m] : 0.f;
            float t1 = (cn[m] >= 2) ? f1[m] : 0.f;
            a[m] = t0 + t1;
            mx = (cn[m] >= 1) ? fmaxf(mx, f0[m]) : mx;
            mx = (cn[m] >= 2) ? fmaxf(mx, f1[m]) : mx;
        }
        // rare tails (cnt >= 3, ~5.5% of voxels)
        if ((cn[0] > 2) || (cn[1] > 2) || (cn[2] > 2) || (cn[3] > 2)) {
            #pragma unroll
            for (int m = 0; m < 4; ++m) {
                for (uint q = 2; q < cn[m]; ++q) {
                    uint iq = s0[m] - S0 + q;
                    int pq = fits ? sPid[iq] : spid[S0 + iq];
                    float fq = feats[(size_t)pq * 32 + ch];
                    a[m] += fq; mx = fmaxf(mx, fq);
                }
            }
        }
        #pragma unroll
        for (int m = 0; m < 4; ++m) {
            int v = vb + 8 * m;
            if (v < STRIP) {
                float fc = cn[m] ? (float)cn[m] : 1.f;
                out[(size_t)(vid0 + v) * 32 + ch] = a[m] * __builtin_amdgcn_rcpf(fc);
            }
        }
    }

    sMx[gi][ch] = mx;
    __syncthreads();
    if (t < 32) {
        float m = sMx[0][t];
        #pragma unroll
        for (int g = 1; g < 8; ++g) m = fmaxf(m, sMx[g][t]);
        if (m != -INFINITY) atomicMax(&agg[c * 32 + t], encF(m));
    }
}

// ---------- kernel 7: agg finalize (decode; untouched/neginf -> 0) ----------
__global__ void k_aggfin(float* outbase) {
    int i = blockIdx.x * blockDim.x + threadIdx.x;     // < NC*32 exactly
    uint* a = (uint*)(outbase + (size_t)VOXT * 32);
    uint e = a[i];
    float f = decF(e);
    if (e == 0u || f == -INFINITY) f = 0.0f;
    ((float*)a)[i] = f;
}

extern "C" void kernel_launch(void* const* d_in, const int* in_sizes, int n_in,
                              void* d_out, int out_size, void* d_ws, size_t ws_size,
                              hipStream_t stream) {
    const float* feats  = (const float*)d_in[0];
    const float* coords = (const float*)d_in[1];
    const void*  cids   = d_in[2];
    const void*  pids   = d_in[3];
    float* out = (float*)d_out;
    char* ws = (char*)d_ws;

    // ws layout (bytes), total 12,440,704 (same footprint as rounds 6/7):
    //   0         double gsum[256*3]       (6144)    } zero
    //   6144      uint   gcnt[256]         (1024)    } zero
    //   7168      uint   gmax[256*3]       (3072)    } zero
    //   10240     uint   vptr[VOXT+1]      (2809860) } zero  -> pad 2820160
    //   2820160   uint   gmin[256*3]       (3072)    0xFF
    //   2823232   double params[256*8]     (16384)
    //   2839616   int    coff[257]         (1028 -> pad 2840704)
    //   2840704   u16    vidl[SPAIRS]      (1200000) -> 4040704
    //   4040704   u16    rankl[SPAIRS]     (1200000) -> 5240704
    //   5240704   float  ccoord[3*SPAIRS]  (7200000) -> 12440704
    //             int    spid[SPAIRS]      (2400000) ALIASES ccoord (dead after k_vox)
    double*   gsum   = (double*)(ws + 0);
    uint*     gcnt   = (uint*)(ws + 6144);
    uint*     gmax   = (uint*)(ws + 7168);
    uint*     vptr   = (uint*)(ws + 10240);
    uint*     gmin   = (uint*)(ws + 2820160);
    double*   params = (double*)(ws + 2823232);
    int*      coff   = (int*)(ws + 2839616);
    ushort_t* vidl   = (ushort_t*)(ws + 2840704);
    ushort_t* rankl  = (ushort_t*)(ws + 4040704);
    float*    ccoord = (float*)(ws + 5240704);
    int*      spid   = (int*)(ws + 5240704);     // alias: ccoord dead before k_scatter
    uint*     agg    = (uint*)(out + (size_t)VOXT * 32);

    hipMemsetAsync(ws, 0, 2820160, stream);               // gsum..vptr(+sentinel)
    hipMemsetAsync((void*)gmin, 0xFF, 3072, stream);      // gmin = +max encodings

    int nb = (SPAIRS + 255) / 256;   // 2344
    k_stats<<<nb, 256, 0, stream>>>(cids, pids, coords, gsum, gcnt, gmin, gmax, ccoord);
    k_params<<<1, 256, 0, stream>>>(gsum, gcnt, gmin, gmax, params, coff);
    k_vox<<<nb, 256, 0, stream>>>(cids, ccoord, params, vidl, rankl, vptr);
    k_scan<<<NC, 256, 0, stream>>>(coff, vptr, agg);
    k_scatter<<<nb, 256, 0, stream>>>(cids, pids, vidl, rankl, vptr, spid);
    k_out<<<NC * 8, 256, 0, stream>>>(feats, vptr, spid, out, agg);
    k_aggfin<<<(NC * 32) / 256, 256, 0, stream>>>(out);
}